// Round 1
// baseline (1460.465 us; speedup 1.0000x reference)
//
#include <hip/hip_runtime.h>

// LatentDynamicsModel fused: in-proj + GRU cell + out-proj.
// I/O fp32; internal GEMM math bf16 MFMA with fp32 accum.
// B=131072, HID=256, LATENT=64, ACTION=2.
// v2: BM=64 rows/block, 512 threads (8 waves), hidden staged once into LDS (bf16).
//  - halves L2 weight traffic (2048 blocks x ~1MB instead of 4096)
//  - 4 MFMAs per weight B-frag load (mt=4) for latency hiding
//  - 2 blocks/CU (LDS 67.6KB), 16 waves/CU with <=128 VGPR cap

typedef unsigned short u16;
typedef unsigned int u32;
using bf16x8 = __attribute__((ext_vector_type(8))) short;  // 8 bf16 (4 VGPRs)
using f32x4  = __attribute__((ext_vector_type(4))) float;  // 4 fp32 acc
using u16x4  = __attribute__((ext_vector_type(4))) unsigned short;

constexpr int B_TOT = 131072;
constexpr int BM    = 64;    // batch rows per block
constexpr int SX    = 264;   // LDS row stride (256 + 8 pad -> 2-way bank aliasing, free)

// d_ws layout (u16 elements)
constexpr int OFF_WIN = 0;        // W_in padded: 256 rows x 72 (src rows of 66, pad 0)
constexpr int OFF_WIH = 18432;    // 768 x 256
constexpr int OFF_WHH = 215040;   // 768 x 256
constexpr int OFF_WO1 = 411648;   // 256 x 256
constexpr int OFF_WO2 = 477184;   // 64 x 256
constexpr int WS_TOT  = 493568;

__device__ __forceinline__ u16 f2b(float f) {  // RNE float->bf16
    u32 u = __builtin_bit_cast(u32, f);
    return (u16)((u + 0x7FFFu + ((u >> 16) & 1u)) >> 16);
}
__device__ __forceinline__ float sigm(float x) {
    x = fminf(fmaxf(x, -30.f), 30.f);
    float e = __expf(x);
    return e * __builtin_amdgcn_rcpf(1.f + e);
}
__device__ __forceinline__ float tanh_(float x) {
    x = fminf(fmaxf(x, -15.f), 15.f);
    float e = __expf(2.f * x);
    return (e - 1.f) * __builtin_amdgcn_rcpf(e + 1.f);
}
__device__ __forceinline__ bf16x8 ld8f_bf(const float* __restrict__ p) {
    float4 a = *reinterpret_cast<const float4*>(p);
    float4 b = *reinterpret_cast<const float4*>(p + 4);
    bf16x8 r;
    r[0] = (short)f2b(a.x); r[1] = (short)f2b(a.y);
    r[2] = (short)f2b(a.z); r[3] = (short)f2b(a.w);
    r[4] = (short)f2b(b.x); r[5] = (short)f2b(b.y);
    r[6] = (short)f2b(b.z); r[7] = (short)f2b(b.w);
    return r;
}
__device__ __forceinline__ float b2f(u16 u) {
    u32 x = (u32)u << 16;
    return __builtin_bit_cast(float, x);
}

#define MFMA(a, b, c) __builtin_amdgcn_mfma_f32_16x16x32_bf16((a), (b), (c), 0, 0, 0)

// ---------- prep: convert all weights fp32 -> bf16 into ws ----------
__global__ void ldm_prep(const float* __restrict__ W_in, const float* __restrict__ W_ih,
                         const float* __restrict__ W_hh, const float* __restrict__ W_o1,
                         const float* __restrict__ W_o2, u16* __restrict__ ws)
{
    int i = blockIdx.x * blockDim.x + threadIdx.x;
    if (i >= WS_TOT) return;
    if (i < OFF_WIH) {                       // W_in padded to stride 72
        int r = i / 72, c = i - r * 72;
        ws[i] = (c < 66) ? f2b(W_in[r * 66 + c]) : (u16)0;
    } else if (i < OFF_WHH) {
        ws[i] = f2b(W_ih[i - OFF_WIH]);
    } else if (i < OFF_WO1) {
        ws[i] = f2b(W_hh[i - OFF_WHH]);
    } else if (i < OFF_WO2) {
        ws[i] = f2b(W_o1[i - OFF_WO1]);
    } else {
        ws[i] = f2b(W_o2[i - OFF_WO2]);
    }
}

// ---------- main fused kernel ----------
__global__ __launch_bounds__(512, 4)
void ldm_fused(const float* __restrict__ z, const float* __restrict__ act,
               const float* __restrict__ hid,
               const float* __restrict__ W_in_f, const float* __restrict__ b_in,
               const float* __restrict__ b_ih, const float* __restrict__ b_hh,
               const float* __restrict__ b_o1, const float* __restrict__ b_o2,
               const u16* __restrict__ ws,
               float* __restrict__ zn_out, float* __restrict__ h_out)
{
    __shared__ u16 xbuf[BM * SX];   // x (bf16), later reused for y
    __shared__ u16 hbuf[BM * SX];   // h (bf16), later overwritten with h_new

    const int tid  = threadIdx.x;
    const int w    = tid >> 6;      // wave 0..7
    const int lane = tid & 63;
    const int l16  = lane & 15;
    const int quad = lane >> 4;
    const int row0 = blockIdx.x * BM;

    const u16* Wib = ws + OFF_WIN;   // padded stride 72
    const u16* Wih = ws + OFF_WIH;
    const u16* Whh = ws + OFF_WHH;
    const u16* Wo1 = ws + OFF_WO1;
    const u16* Wo2 = ws + OFF_WO2;

    // ---- issue cooperative hidden load early (64 rows x 256 f32 = 64KB) ----
    // thread -> row tid>>3, 32 consecutive cols at (tid&7)*32 (8x float4)
    const int hr  = tid >> 3;
    const int hc0 = (tid & 7) * 32;
    float4 hreg[8];
    {
        const float* hp = hid + (size_t)(row0 + hr) * 256 + hc0;
        #pragma unroll
        for (int i = 0; i < 8; ++i)
            hreg[i] = reinterpret_cast<const float4*>(hp)[i];
    }

    // ================= Stage A: x = relu([z|action] @ W_in^T + b_in) =================
    {
        bf16x8 az[4][2];  // [m-tile][k-chunk]
        #pragma unroll
        for (int mt = 0; mt < 4; ++mt) {
            const float* zp = z + (size_t)(row0 + mt * 16 + l16) * 64 + quad * 8;
            az[mt][0] = ld8f_bf(zp);
            az[mt][1] = ld8f_bf(zp + 32);
        }
        #pragma unroll
        for (int ot = 0; ot < 2; ++ot) {
            const int orow = w * 32 + ot * 16 + l16;  // output col / W_in row
            bf16x8 bw[2];
            #pragma unroll
            for (int kc = 0; kc < 2; ++kc)
                bw[kc] = *reinterpret_cast<const bf16x8*>(Wib + orow * 72 + kc * 32 + quad * 8);
            f32x4 acc[4];
            #pragma unroll
            for (int mt = 0; mt < 4; ++mt) acc[mt] = {0.f, 0.f, 0.f, 0.f};
            #pragma unroll
            for (int kc = 0; kc < 2; ++kc)
                #pragma unroll
                for (int mt = 0; mt < 4; ++mt)
                    acc[mt] = MFMA(az[mt][kc], bw[kc], acc[mt]);
            const float w64v = W_in_f[orow * 66 + 64];
            const float w65v = W_in_f[orow * 66 + 65];
            const float bi   = b_in[orow];
            #pragma unroll
            for (int mt = 0; mt < 4; ++mt) {
                #pragma unroll
                for (int i = 0; i < 4; ++i) {
                    const int rl = mt * 16 + quad * 4 + i;
                    const float2 av = reinterpret_cast<const float2*>(act)[row0 + rl];
                    float v = acc[mt][i] + av.x * w64v + av.y * w65v + bi;
                    xbuf[rl * SX + orow] = f2b(fmaxf(v, 0.f));
                }
            }
        }
    }

    // ---- hidden -> LDS (bf16) ----
    {
        #pragma unroll
        for (int i = 0; i < 8; ++i) {
            u16x4 v;
            v[0] = f2b(hreg[i].x); v[1] = f2b(hreg[i].y);
            v[2] = f2b(hreg[i].z); v[3] = f2b(hreg[i].w);
            *reinterpret_cast<u16x4*>(&hbuf[hr * SX + hc0 + i * 4]) = v;
        }
    }
    __syncthreads();

    // ================= Stage B: GRU gates =================
    // Each wave owns 32 output cols; one 16-col tile at a time (16 f32x4 acc live).
    u32 hnpack[2][8];   // h_new bf16, packed pairs: [ot][mt*2 + (i>>1)]
    #pragma unroll 1
    for (int ot = 0; ot < 2; ++ot) {
        const int ob = w * 32 + ot * 16;
        f32x4 aR[4], aZ[4], aNi[4], aNh[4];
        #pragma unroll
        for (int mt = 0; mt < 4; ++mt) {
            aR[mt]  = {0.f, 0.f, 0.f, 0.f};
            aZ[mt]  = {0.f, 0.f, 0.f, 0.f};
            aNi[mt] = {0.f, 0.f, 0.f, 0.f};
            aNh[mt] = {0.f, 0.f, 0.f, 0.f};
        }
        const int r0 = ob + l16;
        // phase X: K over x (A-frags from LDS)
        #pragma unroll
        for (int kc = 0; kc < 8; ++kc) {
            const int ko = kc * 32 + quad * 8;
            bf16x8 ax[4];
            #pragma unroll
            for (int mt = 0; mt < 4; ++mt)
                ax[mt] = *reinterpret_cast<const bf16x8*>(&xbuf[(mt * 16 + l16) * SX + ko]);
            const bf16x8 br_ = *reinterpret_cast<const bf16x8*>(Wih + (size_t)r0 * 256 + ko);
            const bf16x8 bz_ = *reinterpret_cast<const bf16x8*>(Wih + (size_t)(r0 + 256) * 256 + ko);
            const bf16x8 bn_ = *reinterpret_cast<const bf16x8*>(Wih + (size_t)(r0 + 512) * 256 + ko);
            #pragma unroll
            for (int mt = 0; mt < 4; ++mt) {
                aR[mt]  = MFMA(ax[mt], br_, aR[mt]);
                aZ[mt]  = MFMA(ax[mt], bz_, aZ[mt]);
                aNi[mt] = MFMA(ax[mt], bn_, aNi[mt]);
            }
        }
        // phase H: K over h (A-frags from LDS hbuf)
        #pragma unroll
        for (int kc = 0; kc < 8; ++kc) {
            const int ko = kc * 32 + quad * 8;
            bf16x8 ah[4];
            #pragma unroll
            for (int mt = 0; mt < 4; ++mt)
                ah[mt] = *reinterpret_cast<const bf16x8*>(&hbuf[(mt * 16 + l16) * SX + ko]);
            const bf16x8 br_ = *reinterpret_cast<const bf16x8*>(Whh + (size_t)r0 * 256 + ko);
            const bf16x8 bz_ = *reinterpret_cast<const bf16x8*>(Whh + (size_t)(r0 + 256) * 256 + ko);
            const bf16x8 bn_ = *reinterpret_cast<const bf16x8*>(Whh + (size_t)(r0 + 512) * 256 + ko);
            #pragma unroll
            for (int mt = 0; mt < 4; ++mt) {
                aR[mt]  = MFMA(ah[mt], br_, aR[mt]);
                aZ[mt]  = MFMA(ah[mt], bz_, aZ[mt]);
                aNh[mt] = MFMA(ah[mt], bn_, aNh[mt]);
            }
        }
        // gate epilogue (h_new kept in registers, packed bf16)
        {
            const int o = ob + l16;
            const float br_b = b_ih[o]       + b_hh[o];
            const float bz_b = b_ih[o + 256] + b_hh[o + 256];
            const float bni  = b_ih[o + 512];
            const float bnh  = b_hh[o + 512];
            #pragma unroll
            for (int mt = 0; mt < 4; ++mt) {
                u32 pk0 = 0, pk1 = 0;
                #pragma unroll
                for (int i = 0; i < 4; ++i) {
                    const int rl = mt * 16 + quad * 4 + i;
                    const float hv = b2f(hbuf[rl * SX + o]);
                    const float r  = sigm(aR[mt][i] + br_b);
                    const float zg = sigm(aZ[mt][i] + bz_b);
                    const float n  = tanh_(aNi[mt][i] + bni + r * (aNh[mt][i] + bnh));
                    const float hn = n + zg * (hv - n);
                    const u32 hb = f2b(hn);
                    if (i == 0) pk0 = hb;
                    else if (i == 1) pk0 |= hb << 16;
                    else if (i == 2) pk1 = hb;
                    else pk1 |= hb << 16;
                }
                hnpack[ot][mt * 2]     = pk0;
                hnpack[ot][mt * 2 + 1] = pk1;
            }
        }
    }
    __syncthreads();   // all reads of xbuf(x) and hbuf(h) complete

    // scatter h_new into hbuf (overwrite old h)
    #pragma unroll
    for (int ot = 0; ot < 2; ++ot) {
        const int o = w * 32 + ot * 16 + l16;
        #pragma unroll
        for (int mt = 0; mt < 4; ++mt) {
            #pragma unroll
            for (int p = 0; p < 2; ++p) {
                const u32 v = hnpack[ot][mt * 2 + p];
                const int rl = mt * 16 + quad * 4 + p * 2;
                hbuf[rl * SX + o]       = (u16)v;
                hbuf[(rl + 1) * SX + o] = (u16)(v >> 16);
            }
        }
    }
    __syncthreads();

    // coalesced h_new -> global (bf16 LDS -> fp32 stores); issue before Stage 4 compute
    #pragma unroll
    for (int it = 0; it < 4; ++it) {
        const int idx = it * 4096 + tid * 8;
        const int r = idx >> 8, c = idx & 255;
        const bf16x8 v = *reinterpret_cast<const bf16x8*>(&hbuf[r * SX + c]);
        float4 f0, f1;
        f0.x = b2f((u16)v[0]); f0.y = b2f((u16)v[1]); f0.z = b2f((u16)v[2]); f0.w = b2f((u16)v[3]);
        f1.x = b2f((u16)v[4]); f1.y = b2f((u16)v[5]); f1.z = b2f((u16)v[6]); f1.w = b2f((u16)v[7]);
        float* dst = h_out + (size_t)(row0 + r) * 256 + c;
        *reinterpret_cast<float4*>(dst)     = f0;
        *reinterpret_cast<float4*>(dst + 4) = f1;
    }

    // ================= Stage 4: y = relu(h_new @ W_o1^T + b_o1) -> xbuf =================
    #pragma unroll 1
    for (int ot = 0; ot < 2; ++ot) {
        const int o = w * 32 + ot * 16 + l16;
        f32x4 aY[4];
        #pragma unroll
        for (int mt = 0; mt < 4; ++mt) aY[mt] = {0.f, 0.f, 0.f, 0.f};
        #pragma unroll
        for (int kc = 0; kc < 8; ++kc) {
            const int ko = kc * 32 + quad * 8;
            bf16x8 ah2[4];
            #pragma unroll
            for (int mt = 0; mt < 4; ++mt)
                ah2[mt] = *reinterpret_cast<const bf16x8*>(&hbuf[(mt * 16 + l16) * SX + ko]);
            const bf16x8 bo = *reinterpret_cast<const bf16x8*>(Wo1 + (size_t)o * 256 + ko);
            #pragma unroll
            for (int mt = 0; mt < 4; ++mt)
                aY[mt] = MFMA(ah2[mt], bo, aY[mt]);
        }
        const float bo1 = b_o1[o];
        #pragma unroll
        for (int mt = 0; mt < 4; ++mt)
            #pragma unroll
            for (int i = 0; i < 4; ++i) {
                const int rl = mt * 16 + quad * 4 + i;
                xbuf[rl * SX + o] = f2b(fmaxf(aY[mt][i] + bo1, 0.f));
            }
    }
    __syncthreads();

    // ================= Stage 5: z_next = y @ W_o2^T + b_o2 =================
    {
        const int colt = w & 3;          // 4 col tiles of 16 -> 64 output cols
        const int rh   = w >> 2;         // row half (0: rows 0-31, 1: rows 32-63)
        f32x4 aO[2];
        aO[0] = {0.f, 0.f, 0.f, 0.f};
        aO[1] = {0.f, 0.f, 0.f, 0.f};
        const int o = colt * 16 + l16;
        #pragma unroll
        for (int kc = 0; kc < 8; ++kc) {
            const int ko = kc * 32 + quad * 8;
            bf16x8 ay[2];
            #pragma unroll
            for (int mt = 0; mt < 2; ++mt)
                ay[mt] = *reinterpret_cast<const bf16x8*>(&xbuf[(rh * 32 + mt * 16 + l16) * SX + ko]);
            const bf16x8 bo2 = *reinterpret_cast<const bf16x8*>(Wo2 + (size_t)o * 256 + ko);
            aO[0] = MFMA(ay[0], bo2, aO[0]);
            aO[1] = MFMA(ay[1], bo2, aO[1]);
        }
        const float bz2 = b_o2[o];
        #pragma unroll
        for (int mt = 0; mt < 2; ++mt)
            #pragma unroll
            for (int i = 0; i < 4; ++i) {
                const int rl = rh * 32 + mt * 16 + quad * 4 + i;
                zn_out[(size_t)(row0 + rl) * 64 + o] = aO[mt][i] + bz2;
            }
    }
}

extern "C" void kernel_launch(void* const* d_in, const int* in_sizes, int n_in,
                              void* d_out, int out_size, void* d_ws, size_t ws_size,
                              hipStream_t stream) {
    const float* z    = (const float*)d_in[0];
    const float* act  = (const float*)d_in[1];
    const float* hid  = (const float*)d_in[2];
    const float* W_in = (const float*)d_in[3];
    const float* b_in = (const float*)d_in[4];
    const float* W_ih = (const float*)d_in[5];
    const float* W_hh = (const float*)d_in[6];
    const float* b_ih = (const float*)d_in[7];
    const float* b_hh = (const float*)d_in[8];
    const float* W_o1 = (const float*)d_in[9];
    const float* b_o1 = (const float*)d_in[10];
    const float* W_o2 = (const float*)d_in[11];
    const float* b_o2 = (const float*)d_in[12];

    u16* ws = (u16*)d_ws;

    float* zn_out = (float*)d_out;                      // [B, 64]
    float* h_out  = zn_out + (size_t)B_TOT * 64;        // [1, B, 256]

    ldm_prep<<<dim3((WS_TOT + 255) / 256), dim3(256), 0, stream>>>(
        W_in, W_ih, W_hh, W_o1, W_o2, ws);

    ldm_fused<<<dim3(B_TOT / BM), dim3(512), 0, stream>>>(
        z, act, hid, W_in, b_in, b_ih, b_hh, b_o1, b_o2, ws, zn_out, h_out);
}

// Round 2
// 693.273 us; speedup vs baseline: 2.1066x; 2.1066x over previous
//
#include <hip/hip_runtime.h>

// LatentDynamicsModel fused: in-proj + GRU cell + out-proj.
// I/O fp32; internal GEMM math bf16 MFMA with fp32 accum.
// B=131072, HID=256, LATENT=64, ACTION=2.
// v3: BM=64 rows/block, 512 threads (8 waves), hidden staged once into LDS (bf16).
//     Stage B restructured into TWO PASSES (2 acc sets each, not 4) so peak live
//     registers ~110 < 128 cap of __launch_bounds__(512,4) -> no scratch spills
//     (v2's 64-VGPR alloc spilled ~2.4GB of scratch traffic).
//     All register arrays statically indexed (manual ot unroll, rule #20).

typedef unsigned short u16;
typedef unsigned int u32;
using bf16x8 = __attribute__((ext_vector_type(8))) short;  // 8 bf16 (4 VGPRs)
using f32x4  = __attribute__((ext_vector_type(4))) float;  // 4 fp32 acc
using u16x4  = __attribute__((ext_vector_type(4))) unsigned short;

constexpr int B_TOT = 131072;
constexpr int BM    = 64;    // batch rows per block
constexpr int SX    = 264;   // LDS row stride (256 + 8 pad -> 2-way bank aliasing, free)

// d_ws layout (u16 elements)
constexpr int OFF_WIN = 0;        // W_in padded: 256 rows x 72 (src rows of 66, pad 0)
constexpr int OFF_WIH = 18432;    // 768 x 256
constexpr int OFF_WHH = 215040;   // 768 x 256
constexpr int OFF_WO1 = 411648;   // 256 x 256
constexpr int OFF_WO2 = 477184;   // 64 x 256
constexpr int WS_TOT  = 493568;

__device__ __forceinline__ u16 f2b(float f) {  // RNE float->bf16
    u32 u = __builtin_bit_cast(u32, f);
    return (u16)((u + 0x7FFFu + ((u >> 16) & 1u)) >> 16);
}
__device__ __forceinline__ float sigm(float x) {
    x = fminf(fmaxf(x, -30.f), 30.f);
    float e = __expf(x);
    return e * __builtin_amdgcn_rcpf(1.f + e);
}
__device__ __forceinline__ float tanh_(float x) {
    x = fminf(fmaxf(x, -15.f), 15.f);
    float e = __expf(2.f * x);
    return (e - 1.f) * __builtin_amdgcn_rcpf(e + 1.f);
}
__device__ __forceinline__ bf16x8 ld8f_bf(const float* __restrict__ p) {
    float4 a = *reinterpret_cast<const float4*>(p);
    float4 b = *reinterpret_cast<const float4*>(p + 4);
    bf16x8 r;
    r[0] = (short)f2b(a.x); r[1] = (short)f2b(a.y);
    r[2] = (short)f2b(a.z); r[3] = (short)f2b(a.w);
    r[4] = (short)f2b(b.x); r[5] = (short)f2b(b.y);
    r[6] = (short)f2b(b.z); r[7] = (short)f2b(b.w);
    return r;
}
__device__ __forceinline__ float b2f(u16 u) {
    u32 x = (u32)u << 16;
    return __builtin_bit_cast(float, x);
}

#define MFMA(a, b, c) __builtin_amdgcn_mfma_f32_16x16x32_bf16((a), (b), (c), 0, 0, 0)

// ---------- prep: convert all weights fp32 -> bf16 into ws ----------
__global__ void ldm_prep(const float* __restrict__ W_in, const float* __restrict__ W_ih,
                         const float* __restrict__ W_hh, const float* __restrict__ W_o1,
                         const float* __restrict__ W_o2, u16* __restrict__ ws)
{
    int i = blockIdx.x * blockDim.x + threadIdx.x;
    if (i >= WS_TOT) return;
    if (i < OFF_WIH) {                       // W_in padded to stride 72
        int r = i / 72, c = i - r * 72;
        ws[i] = (c < 66) ? f2b(W_in[r * 66 + c]) : (u16)0;
    } else if (i < OFF_WHH) {
        ws[i] = f2b(W_ih[i - OFF_WIH]);
    } else if (i < OFF_WO1) {
        ws[i] = f2b(W_hh[i - OFF_WHH]);
    } else if (i < OFF_WO2) {
        ws[i] = f2b(W_o1[i - OFF_WO1]);
    } else {
        ws[i] = f2b(W_o2[i - OFF_WO2]);
    }
}

// ---------- main fused kernel ----------
__global__ __launch_bounds__(512, 4)
void ldm_fused(const float* __restrict__ z, const float* __restrict__ act,
               const float* __restrict__ hid,
               const float* __restrict__ W_in_f, const float* __restrict__ b_in,
               const float* __restrict__ b_ih, const float* __restrict__ b_hh,
               const float* __restrict__ b_o1, const float* __restrict__ b_o2,
               const u16* __restrict__ ws,
               float* __restrict__ zn_out, float* __restrict__ h_out)
{
    __shared__ u16 xbuf[BM * SX];   // x (bf16), later reused for y
    __shared__ u16 hbuf[BM * SX];   // h (bf16), later overwritten with h_new

    const int tid  = threadIdx.x;
    const int w    = tid >> 6;      // wave 0..7
    const int lane = tid & 63;
    const int l16  = lane & 15;
    const int quad = lane >> 4;
    const int row0 = blockIdx.x * BM;

    const u16* Wib = ws + OFF_WIN;   // padded stride 72
    const u16* Wih = ws + OFF_WIH;
    const u16* Whh = ws + OFF_WHH;
    const u16* Wo1 = ws + OFF_WO1;
    const u16* Wo2 = ws + OFF_WO2;

    // ---- issue cooperative hidden load early (64 rows x 256 f32 = 64KB) ----
    const int hr  = tid >> 3;
    const int hc0 = (tid & 7) * 32;
    float4 hreg[8];
    {
        const float* hp = hid + (size_t)(row0 + hr) * 256 + hc0;
        #pragma unroll
        for (int i = 0; i < 8; ++i)
            hreg[i] = reinterpret_cast<const float4*>(hp)[i];
    }

    // ================= Stage A: x = relu([z|action] @ W_in^T + b_in) =================
    {
        bf16x8 az[4][2];  // [m-tile][k-chunk]
        #pragma unroll
        for (int mt = 0; mt < 4; ++mt) {
            const float* zp = z + (size_t)(row0 + mt * 16 + l16) * 64 + quad * 8;
            az[mt][0] = ld8f_bf(zp);
            az[mt][1] = ld8f_bf(zp + 32);
        }
        #pragma unroll
        for (int ot = 0; ot < 2; ++ot) {
            const int orow = w * 32 + ot * 16 + l16;  // output col / W_in row
            bf16x8 bw[2];
            #pragma unroll
            for (int kc = 0; kc < 2; ++kc)
                bw[kc] = *reinterpret_cast<const bf16x8*>(Wib + orow * 72 + kc * 32 + quad * 8);
            f32x4 acc[4];
            #pragma unroll
            for (int mt = 0; mt < 4; ++mt) acc[mt] = {0.f, 0.f, 0.f, 0.f};
            #pragma unroll
            for (int kc = 0; kc < 2; ++kc)
                #pragma unroll
                for (int mt = 0; mt < 4; ++mt)
                    acc[mt] = MFMA(az[mt][kc], bw[kc], acc[mt]);
            const float w64v = W_in_f[orow * 66 + 64];
            const float w65v = W_in_f[orow * 66 + 65];
            const float bi   = b_in[orow];
            #pragma unroll
            for (int mt = 0; mt < 4; ++mt) {
                #pragma unroll
                for (int i = 0; i < 4; ++i) {
                    const int rl = mt * 16 + quad * 4 + i;
                    const float2 av = reinterpret_cast<const float2*>(act)[row0 + rl];
                    float v = acc[mt][i] + av.x * w64v + av.y * w65v + bi;
                    xbuf[rl * SX + orow] = f2b(fmaxf(v, 0.f));
                }
            }
        }
    }

    // ---- hidden -> LDS (bf16) ----
    {
        #pragma unroll
        for (int i = 0; i < 8; ++i) {
            u16x4 v;
            v[0] = f2b(hreg[i].x); v[1] = f2b(hreg[i].y);
            v[2] = f2b(hreg[i].z); v[3] = f2b(hreg[i].w);
            *reinterpret_cast<u16x4*>(&hbuf[hr * SX + hc0 + i * 4]) = v;
        }
    }
    __syncthreads();

    // ================= Stage B: GRU gates, two passes per 16-col tile =================
    // Pass 1: gR = x*Wih_r + h*Whh_r ; gNh = h*Whh_n  -> rhn = sigm(gR+b)*(gNh+bnh)
    // Pass 2: gZ = x*Wih_z + h*Whh_z ; gNi = x*Wih_n  -> full epilogue
    u32 hnp0[8], hnp1[8];   // h_new bf16 packed pairs, per ot tile (statically indexed)

    auto gru_tile = [&](const int ot, u32 (&pk)[8]) {
        const int o  = w * 32 + ot * 16 + l16;   // output col / weight row
        f32x4 rhn[4];
        // ---- pass 1 ----
        {
            f32x4 gR[4], gNh[4];
            #pragma unroll
            for (int mt = 0; mt < 4; ++mt) {
                gR[mt]  = {0.f, 0.f, 0.f, 0.f};
                gNh[mt] = {0.f, 0.f, 0.f, 0.f};
            }
            #pragma unroll
            for (int kc = 0; kc < 8; ++kc) {           // phase X: K over x
                const int ko = kc * 32 + quad * 8;
                bf16x8 ax[4];
                #pragma unroll
                for (int mt = 0; mt < 4; ++mt)
                    ax[mt] = *reinterpret_cast<const bf16x8*>(&xbuf[(mt * 16 + l16) * SX + ko]);
                const bf16x8 br_ = *reinterpret_cast<const bf16x8*>(Wih + (size_t)o * 256 + ko);
                #pragma unroll
                for (int mt = 0; mt < 4; ++mt)
                    gR[mt] = MFMA(ax[mt], br_, gR[mt]);
            }
            #pragma unroll
            for (int kc = 0; kc < 8; ++kc) {           // phase H: K over h
                const int ko = kc * 32 + quad * 8;
                bf16x8 ah[4];
                #pragma unroll
                for (int mt = 0; mt < 4; ++mt)
                    ah[mt] = *reinterpret_cast<const bf16x8*>(&hbuf[(mt * 16 + l16) * SX + ko]);
                const bf16x8 br_ = *reinterpret_cast<const bf16x8*>(Whh + (size_t)o * 256 + ko);
                const bf16x8 bn_ = *reinterpret_cast<const bf16x8*>(Whh + (size_t)(o + 512) * 256 + ko);
                #pragma unroll
                for (int mt = 0; mt < 4; ++mt) {
                    gR[mt]  = MFMA(ah[mt], br_, gR[mt]);
                    gNh[mt] = MFMA(ah[mt], bn_, gNh[mt]);
                }
            }
            const float br_b = b_ih[o] + b_hh[o];
            const float bnh  = b_hh[o + 512];
            #pragma unroll
            for (int mt = 0; mt < 4; ++mt)
                #pragma unroll
                for (int i = 0; i < 4; ++i) {
                    const float r = sigm(gR[mt][i] + br_b);
                    rhn[mt][i] = r * (gNh[mt][i] + bnh);
                }
        }
        // ---- pass 2 ----
        {
            f32x4 gZ[4], gNi[4];
            #pragma unroll
            for (int mt = 0; mt < 4; ++mt) {
                gZ[mt]  = {0.f, 0.f, 0.f, 0.f};
                gNi[mt] = {0.f, 0.f, 0.f, 0.f};
            }
            #pragma unroll
            for (int kc = 0; kc < 8; ++kc) {           // phase X: K over x
                const int ko = kc * 32 + quad * 8;
                bf16x8 ax[4];
                #pragma unroll
                for (int mt = 0; mt < 4; ++mt)
                    ax[mt] = *reinterpret_cast<const bf16x8*>(&xbuf[(mt * 16 + l16) * SX + ko]);
                const bf16x8 bz_ = *reinterpret_cast<const bf16x8*>(Wih + (size_t)(o + 256) * 256 + ko);
                const bf16x8 bn_ = *reinterpret_cast<const bf16x8*>(Wih + (size_t)(o + 512) * 256 + ko);
                #pragma unroll
                for (int mt = 0; mt < 4; ++mt) {
                    gZ[mt]  = MFMA(ax[mt], bz_, gZ[mt]);
                    gNi[mt] = MFMA(ax[mt], bn_, gNi[mt]);
                }
            }
            #pragma unroll
            for (int kc = 0; kc < 8; ++kc) {           // phase H: K over h
                const int ko = kc * 32 + quad * 8;
                bf16x8 ah[4];
                #pragma unroll
                for (int mt = 0; mt < 4; ++mt)
                    ah[mt] = *reinterpret_cast<const bf16x8*>(&hbuf[(mt * 16 + l16) * SX + ko]);
                const bf16x8 bz_ = *reinterpret_cast<const bf16x8*>(Whh + (size_t)(o + 256) * 256 + ko);
                #pragma unroll
                for (int mt = 0; mt < 4; ++mt)
                    gZ[mt] = MFMA(ah[mt], bz_, gZ[mt]);
            }
            const float bz_b = b_ih[o + 256] + b_hh[o + 256];
            const float bni  = b_ih[o + 512];
            #pragma unroll
            for (int mt = 0; mt < 4; ++mt) {
                u32 pk0 = 0, pk1 = 0;
                #pragma unroll
                for (int i = 0; i < 4; ++i) {
                    const int rl = mt * 16 + quad * 4 + i;
                    const float hv = b2f(hbuf[rl * SX + o]);
                    const float zg = sigm(gZ[mt][i] + bz_b);
                    const float n  = tanh_(gNi[mt][i] + bni + rhn[mt][i]);
                    const float hn = n + zg * (hv - n);
                    const u32 hb = f2b(hn);
                    if (i == 0) pk0 = hb;
                    else if (i == 1) pk0 |= hb << 16;
                    else if (i == 2) pk1 = hb;
                    else pk1 |= hb << 16;
                }
                pk[mt * 2]     = pk0;
                pk[mt * 2 + 1] = pk1;
            }
        }
    };

    gru_tile(0, hnp0);
    __builtin_amdgcn_sched_barrier(0);   // keep the two tiles' live ranges separate
    gru_tile(1, hnp1);

    __syncthreads();   // all reads of xbuf(x) and hbuf(h) complete

    // scatter h_new into hbuf (overwrite old h); static indexing via manual unroll
    auto scat = [&](const int ot, const u32 (&pk)[8]) {
        const int o = w * 32 + ot * 16 + l16;
        #pragma unroll
        for (int mt = 0; mt < 4; ++mt) {
            #pragma unroll
            for (int p = 0; p < 2; ++p) {
                const u32 v = pk[mt * 2 + p];
                const int rl = mt * 16 + quad * 4 + p * 2;
                hbuf[rl * SX + o]       = (u16)v;
                hbuf[(rl + 1) * SX + o] = (u16)(v >> 16);
            }
        }
    };
    scat(0, hnp0);
    scat(1, hnp1);
    __syncthreads();

    // coalesced h_new -> global (bf16 LDS -> fp32 stores); issued before Stage 4 compute
    #pragma unroll
    for (int it = 0; it < 4; ++it) {
        const int idx = it * 4096 + tid * 8;
        const int r = idx >> 8, c = idx & 255;
        const bf16x8 v = *reinterpret_cast<const bf16x8*>(&hbuf[r * SX + c]);
        float4 f0, f1;
        f0.x = b2f((u16)v[0]); f0.y = b2f((u16)v[1]); f0.z = b2f((u16)v[2]); f0.w = b2f((u16)v[3]);
        f1.x = b2f((u16)v[4]); f1.y = b2f((u16)v[5]); f1.z = b2f((u16)v[6]); f1.w = b2f((u16)v[7]);
        float* dst = h_out + (size_t)(row0 + r) * 256 + c;
        *reinterpret_cast<float4*>(dst)     = f0;
        *reinterpret_cast<float4*>(dst + 4) = f1;
    }

    // ================= Stage 4: y = relu(h_new @ W_o1^T + b_o1) -> xbuf =================
    #pragma unroll 1
    for (int ot = 0; ot < 2; ++ot) {
        const int o = w * 32 + ot * 16 + l16;
        f32x4 aY[4];
        #pragma unroll
        for (int mt = 0; mt < 4; ++mt) aY[mt] = {0.f, 0.f, 0.f, 0.f};
        #pragma unroll
        for (int kc = 0; kc < 8; ++kc) {
            const int ko = kc * 32 + quad * 8;
            bf16x8 ah2[4];
            #pragma unroll
            for (int mt = 0; mt < 4; ++mt)
                ah2[mt] = *reinterpret_cast<const bf16x8*>(&hbuf[(mt * 16 + l16) * SX + ko]);
            const bf16x8 bo = *reinterpret_cast<const bf16x8*>(Wo1 + (size_t)o * 256 + ko);
            #pragma unroll
            for (int mt = 0; mt < 4; ++mt)
                aY[mt] = MFMA(ah2[mt], bo, aY[mt]);
        }
        const float bo1 = b_o1[o];
        #pragma unroll
        for (int mt = 0; mt < 4; ++mt)
            #pragma unroll
            for (int i = 0; i < 4; ++i) {
                const int rl = mt * 16 + quad * 4 + i;
                xbuf[rl * SX + o] = f2b(fmaxf(aY[mt][i] + bo1, 0.f));
            }
    }
    __syncthreads();

    // ================= Stage 5: z_next = y @ W_o2^T + b_o2 =================
    {
        const int colt = w & 3;          // 4 col tiles of 16 -> 64 output cols
        const int rh   = w >> 2;         // row half (0: rows 0-31, 1: rows 32-63)
        f32x4 aO[2];
        aO[0] = {0.f, 0.f, 0.f, 0.f};
        aO[1] = {0.f, 0.f, 0.f, 0.f};
        const int o = colt * 16 + l16;
        #pragma unroll
        for (int kc = 0; kc < 8; ++kc) {
            const int ko = kc * 32 + quad * 8;
            bf16x8 ay[2];
            #pragma unroll
            for (int mt = 0; mt < 2; ++mt)
                ay[mt] = *reinterpret_cast<const bf16x8*>(&xbuf[(rh * 32 + mt * 16 + l16) * SX + ko]);
            const bf16x8 bo2 = *reinterpret_cast<const bf16x8*>(Wo2 + (size_t)o * 256 + ko);
            aO[0] = MFMA(ay[0], bo2, aO[0]);
            aO[1] = MFMA(ay[1], bo2, aO[1]);
        }
        const float bz2 = b_o2[o];
        #pragma unroll
        for (int mt = 0; mt < 2; ++mt)
            #pragma unroll
            for (int i = 0; i < 4; ++i) {
                const int rl = rh * 32 + mt * 16 + quad * 4 + i;
                zn_out[(size_t)(row0 + rl) * 64 + o] = aO[mt][i] + bz2;
            }
    }
}

extern "C" void kernel_launch(void* const* d_in, const int* in_sizes, int n_in,
                              void* d_out, int out_size, void* d_ws, size_t ws_size,
                              hipStream_t stream) {
    const float* z    = (const float*)d_in[0];
    const float* act  = (const float*)d_in[1];
    const float* hid  = (const float*)d_in[2];
    const float* W_in = (const float*)d_in[3];
    const float* b_in = (const float*)d_in[4];
    const float* W_ih = (const float*)d_in[5];
    const float* W_hh = (const float*)d_in[6];
    const float* b_ih = (const float*)d_in[7];
    const float* b_hh = (const float*)d_in[8];
    const float* W_o1 = (const float*)d_in[9];
    const float* b_o1 = (const float*)d_in[10];
    const float* W_o2 = (const float*)d_in[11];
    const float* b_o2 = (const float*)d_in[12];

    u16* ws = (u16*)d_ws;

    float* zn_out = (float*)d_out;                      // [B, 64]
    float* h_out  = zn_out + (size_t)B_TOT * 64;        // [1, B, 256]

    ldm_prep<<<dim3((WS_TOT + 255) / 256), dim3(256), 0, stream>>>(
        W_in, W_ih, W_hh, W_o1, W_o2, ws);

    ldm_fused<<<dim3(B_TOT / BM), dim3(512), 0, stream>>>(
        z, act, hid, W_in, b_in, b_ih, b_hh, b_o1, b_o2, ws, zn_out, h_out);
}

// Round 3
// 476.184 us; speedup vs baseline: 3.0670x; 1.4559x over previous
//
#include <hip/hip_runtime.h>

// LatentDynamicsModel fused: in-proj + GRU cell + out-proj.
// I/O fp32; internal GEMM math bf16 MFMA with fp32 accum.
// B=131072, HID=256, LATENT=64, ACTION=2.
// v4: fragment-linear everything.
//  - Weights pre-swizzled in ldm_prep into MFMA B-frag order: (tile,kc) block is
//    1KB contiguous, wave load = base + lane*16B (coalesced, 1 addr/wave).
//    [Wih|Whh] concatenated per gate -> single K=512 stream per gate.
//  - x and h live in ONE frag-linear LDS buffer xh (64KB): ds_read_b128 at
//    lane*16 -> zero bank conflicts, minimal address math.
//  - Stage B k-loops prefetch weight frags in batches of 8 / 2x4 named regs
//    (statically indexed) so ~8 loads are in flight under the MFMAs.
//  - BM=64, 512 threads (8 waves), 2 blocks/CU, __launch_bounds__(512,4).

typedef unsigned short u16;
typedef unsigned int u32;
using bf16x8 = __attribute__((ext_vector_type(8))) short;  // 8 bf16 (4 VGPRs)
using f32x4  = __attribute__((ext_vector_type(4))) float;  // 4 fp32 acc
using u16x4  = __attribute__((ext_vector_type(4))) unsigned short;

constexpr int B_TOT = 131072;
constexpr int BM    = 64;    // batch rows per block

// frag-linear ws layout (u16 units). A (tile,kc) block = 64 lanes x 8 u16 = 512.
constexpr int OFF_WIN = 0;                  // 16 tiles x 2 kc x 512 = 16384
constexpr int OFF_WG  = 16384;              // 48 gate-tiles x 16 kc x 512 = 393216 ([Wih|Whh] per gate r,z,n)
constexpr int OFF_WO1 = 409600;             // 16 tiles x 8 kc x 512 = 65536
constexpr int OFF_WO2 = 475136;             // 4 tiles x 8 kc x 512 = 16384
constexpr int WS_TOT  = 491520;

__device__ __forceinline__ u16 f2b(float f) {  // RNE float->bf16
    u32 u = __builtin_bit_cast(u32, f);
    return (u16)((u + 0x7FFFu + ((u >> 16) & 1u)) >> 16);
}
__device__ __forceinline__ float sigm(float x) {
    x = fminf(fmaxf(x, -30.f), 30.f);
    float e = __expf(x);
    return e * __builtin_amdgcn_rcpf(1.f + e);
}
__device__ __forceinline__ float tanh_(float x) {
    x = fminf(fmaxf(x, -15.f), 15.f);
    float e = __expf(2.f * x);
    return (e - 1.f) * __builtin_amdgcn_rcpf(e + 1.f);
}
__device__ __forceinline__ bf16x8 ld8f_bf(const float* __restrict__ p) {
    float4 a = *reinterpret_cast<const float4*>(p);
    float4 b = *reinterpret_cast<const float4*>(p + 4);
    bf16x8 r;
    r[0] = (short)f2b(a.x); r[1] = (short)f2b(a.y);
    r[2] = (short)f2b(a.z); r[3] = (short)f2b(a.w);
    r[4] = (short)f2b(b.x); r[5] = (short)f2b(b.y);
    r[6] = (short)f2b(b.z); r[7] = (short)f2b(b.w);
    return r;
}
__device__ __forceinline__ float b2f(u16 u) {
    u32 x = (u32)u << 16;
    return __builtin_bit_cast(float, x);
}
// scalar element (row 0..63, virtual-k 0..511; x cols = 0..255, h cols = 256..511)
__device__ __forceinline__ int fidx(int row, int kv) {
    return ((row >> 4) * 16 + (kv >> 5)) * 512 + ((kv >> 3) & 3) * 128 + (row & 15) * 8 + (kv & 7);
}

#define MFMA(a, b, c) __builtin_amdgcn_mfma_f32_16x16x32_bf16((a), (b), (c), 0, 0, 0)

// ---------- prep: fp32 -> bf16 + swizzle into MFMA B-frag linear layout ----------
// Frag element (tile, kc, lane, e) holds W[tile*16 + (lane&15)][kc*32 + (lane>>4)*8 + e].
__global__ void ldm_prep(const float* __restrict__ W_in, const float* __restrict__ W_ih,
                         const float* __restrict__ W_hh, const float* __restrict__ W_o1,
                         const float* __restrict__ W_o2, u16* __restrict__ ws)
{
    int i = blockIdx.x * blockDim.x + threadIdx.x;
    if (i >= WS_TOT) return;
    const int lane = (i >> 3) & 63;
    const int e    = i & 7;
    const int lrow = lane & 15;
    const int kq   = (lane >> 4) * 8 + e;     // k offset within the 32-wide kc block
    float v;
    if (i < OFF_WG) {                          // W_in (K=64, 2 kc blocks per tile)
        const int blk = i >> 9;
        const int kc = blk & 1, t = blk >> 1;
        v = W_in[(t * 16 + lrow) * 66 + kc * 32 + kq];
    } else if (i < OFF_WO1) {                  // gates: [Wih | Whh], K=512 (16 kc blocks)
        const int j = i - OFF_WG;
        const int blk = j >> 9;
        const int kc16 = blk & 15, gt = blk >> 4;
        const int g = gt >> 4, t = gt & 15;
        const int grow = g * 256 + t * 16 + lrow;
        const int k = (kc16 & 7) * 32 + kq;
        v = (kc16 < 8) ? W_ih[grow * 256 + k] : W_hh[grow * 256 + k];
    } else if (i < OFF_WO2) {                  // W_o1 (K=256, 8 kc blocks)
        const int j = i - OFF_WO1;
        const int blk = j >> 9;
        const int kc = blk & 7, t = blk >> 3;
        v = W_o1[(t * 16 + lrow) * 256 + kc * 32 + kq];
    } else {                                   // W_o2 (64 rows, K=256)
        const int j = i - OFF_WO2;
        const int blk = j >> 9;
        const int kc = blk & 7, t = blk >> 3;
        v = W_o2[(t * 16 + lrow) * 256 + kc * 32 + kq];
    }
    ws[i] = f2b(v);
}

// ---------- main fused kernel ----------
__global__ __launch_bounds__(512, 4)
void ldm_fused(const float* __restrict__ z, const float* __restrict__ act,
               const float* __restrict__ hid,
               const float* __restrict__ W_in_f, const float* __restrict__ b_in,
               const float* __restrict__ b_ih, const float* __restrict__ b_hh,
               const float* __restrict__ b_o1, const float* __restrict__ b_o2,
               const u16* __restrict__ ws,
               float* __restrict__ zn_out, float* __restrict__ h_out)
{
    // merged frag-linear activation buffer: virtual-k 0..255 = x, 256..511 = h (64KB)
    __shared__ u16 xh[4 * 16 * 512];

    const int tid  = threadIdx.x;
    const int w    = tid >> 6;      // wave 0..7
    const int lane = tid & 63;
    const int l16  = lane & 15;
    const int quad = lane >> 4;
    const int row0 = blockIdx.x * BM;
    const int lofs = lane * 8;      // u16 offset of this lane's frag slot

    // ---- issue cooperative hidden load early (64 rows x 256 f32 = 64KB) ----
    const int hr  = tid >> 3;
    const int hc0 = (tid & 7) * 32;
    float4 hreg[8];
    {
        const float* hp = hid + (size_t)(row0 + hr) * 256 + hc0;
        #pragma unroll
        for (int i = 0; i < 8; ++i)
            hreg[i] = reinterpret_cast<const float4*>(hp)[i];
    }

    // ================= Stage A: x = relu([z|action] @ W_in^T + b_in) =================
    {
        bf16x8 az[4][2];  // [m-tile][k-chunk]
        #pragma unroll
        for (int mt = 0; mt < 4; ++mt) {
            const float* zp = z + (size_t)(row0 + mt * 16 + l16) * 64 + quad * 8;
            az[mt][0] = ld8f_bf(zp);
            az[mt][1] = ld8f_bf(zp + 32);
        }
        #pragma unroll
        for (int ot = 0; ot < 2; ++ot) {
            const int T = w * 2 + ot;
            const int orow = T * 16 + l16;  // output col / W_in row
            bf16x8 bw[2];
            #pragma unroll
            for (int kc = 0; kc < 2; ++kc)
                bw[kc] = *reinterpret_cast<const bf16x8*>(ws + OFF_WIN + (T * 2 + kc) * 512 + lofs);
            f32x4 acc[4];
            #pragma unroll
            for (int mt = 0; mt < 4; ++mt) acc[mt] = {0.f, 0.f, 0.f, 0.f};
            #pragma unroll
            for (int kc = 0; kc < 2; ++kc)
                #pragma unroll
                for (int mt = 0; mt < 4; ++mt)
                    acc[mt] = MFMA(az[mt][kc], bw[kc], acc[mt]);
            const float w64v = W_in_f[orow * 66 + 64];
            const float w65v = W_in_f[orow * 66 + 65];
            const float bi   = b_in[orow];
            #pragma unroll
            for (int mt = 0; mt < 4; ++mt) {
                #pragma unroll
                for (int i = 0; i < 4; ++i) {
                    const int rl = mt * 16 + quad * 4 + i;
                    const float2 av = reinterpret_cast<const float2*>(act)[row0 + rl];
                    float v = acc[mt][i] + av.x * w64v + av.y * w65v + bi;
                    xh[fidx(rl, orow)] = f2b(fmaxf(v, 0.f));
                }
            }
        }
    }

    // ---- hidden -> LDS (bf16, frag layout, virtual-k 256+c) ----
    {
        #pragma unroll
        for (int i = 0; i < 8; ++i) {
            u16x4 v;
            v[0] = f2b(hreg[i].x); v[1] = f2b(hreg[i].y);
            v[2] = f2b(hreg[i].z); v[3] = f2b(hreg[i].w);
            *reinterpret_cast<u16x4*>(&xh[fidx(hr, 256 + hc0 + i * 4)]) = v;
        }
    }
    __syncthreads();

    // ================= Stage B: GRU gates, two passes per 16-col tile =================
    // Gate weight stream g = [Wih_g | Whh_g], K=512 (kc 0..15); xh holds [x | h].
    // Pass 1: gR over kc 0..15; gNh over kc 8..15  -> rhn = sigm(gR+b)*(gNh+bnh)
    // Pass 2: gZ over kc 0..15; gNi over kc 0..7   -> full epilogue
    u32 hnp0[8], hnp1[8];

    auto gru_tile = [&](const int ot, u32 (&pk)[8]) {
        const int T = w * 2 + ot;
        const int o = T * 16 + l16;                 // output col
        const u16* WR = ws + OFF_WG + (size_t)((0  + T) * 16) * 512 + lofs;
        const u16* WZ = ws + OFF_WG + (size_t)((16 + T) * 16) * 512 + lofs;
        const u16* WN = ws + OFF_WG + (size_t)((32 + T) * 16) * 512 + lofs;

        f32x4 rhn[4];
        // ---- pass 1 ----
        {
            f32x4 gR[4], gNh[4];
            #pragma unroll
            for (int mt = 0; mt < 4; ++mt) {
                gR[mt]  = {0.f, 0.f, 0.f, 0.f};
                gNh[mt] = {0.f, 0.f, 0.f, 0.f};
            }
            {   // kc 0..7: gate R only (8 frags prefetched)
                bf16x8 wr[8];
                #pragma unroll
                for (int j = 0; j < 8; ++j)
                    wr[j] = *reinterpret_cast<const bf16x8*>(WR + j * 512);
                #pragma unroll
                for (int j = 0; j < 8; ++j) {
                    bf16x8 ax[4];
                    #pragma unroll
                    for (int mt = 0; mt < 4; ++mt)
                        ax[mt] = *reinterpret_cast<const bf16x8*>(&xh[(mt * 16 + j) * 512 + lofs]);
                    #pragma unroll
                    for (int mt = 0; mt < 4; ++mt)
                        gR[mt] = MFMA(ax[mt], wr[j], gR[mt]);
                }
            }
            #pragma unroll
            for (int h4 = 0; h4 < 2; ++h4) {   // kc 8..15: gates R + N (2x4 frags each)
                bf16x8 wr[4], wn[4];
                #pragma unroll
                for (int j = 0; j < 4; ++j) {
                    wr[j] = *reinterpret_cast<const bf16x8*>(WR + (8 + h4 * 4 + j) * 512);
                    wn[j] = *reinterpret_cast<const bf16x8*>(WN + (8 + h4 * 4 + j) * 512);
                }
                #pragma unroll
                for (int j = 0; j < 4; ++j) {
                    const int kc = 8 + h4 * 4 + j;
                    bf16x8 ah[4];
                    #pragma unroll
                    for (int mt = 0; mt < 4; ++mt)
                        ah[mt] = *reinterpret_cast<const bf16x8*>(&xh[(mt * 16 + kc) * 512 + lofs]);
                    #pragma unroll
                    for (int mt = 0; mt < 4; ++mt) {
                        gR[mt]  = MFMA(ah[mt], wr[j], gR[mt]);
                        gNh[mt] = MFMA(ah[mt], wn[j], gNh[mt]);
                    }
                }
            }
            const float br_b = b_ih[o] + b_hh[o];
            const float bnh  = b_hh[o + 512];
            #pragma unroll
            for (int mt = 0; mt < 4; ++mt)
                #pragma unroll
                for (int i = 0; i < 4; ++i) {
                    const float r = sigm(gR[mt][i] + br_b);
                    rhn[mt][i] = r * (gNh[mt][i] + bnh);
                }
        }
        // ---- pass 2 ----
        {
            f32x4 gZ[4], gNi[4];
            #pragma unroll
            for (int mt = 0; mt < 4; ++mt) {
                gZ[mt]  = {0.f, 0.f, 0.f, 0.f};
                gNi[mt] = {0.f, 0.f, 0.f, 0.f};
            }
            #pragma unroll
            for (int h4 = 0; h4 < 2; ++h4) {   // kc 0..7: gates Z + Ni
                bf16x8 wz[4], wn[4];
                #pragma unroll
                for (int j = 0; j < 4; ++j) {
                    wz[j] = *reinterpret_cast<const bf16x8*>(WZ + (h4 * 4 + j) * 512);
                    wn[j] = *reinterpret_cast<const bf16x8*>(WN + (h4 * 4 + j) * 512);
                }
                #pragma unroll
                for (int j = 0; j < 4; ++j) {
                    const int kc = h4 * 4 + j;
                    bf16x8 ax[4];
                    #pragma unroll
                    for (int mt = 0; mt < 4; ++mt)
                        ax[mt] = *reinterpret_cast<const bf16x8*>(&xh[(mt * 16 + kc) * 512 + lofs]);
                    #pragma unroll
                    for (int mt = 0; mt < 4; ++mt) {
                        gZ[mt]  = MFMA(ax[mt], wz[j], gZ[mt]);
                        gNi[mt] = MFMA(ax[mt], wn[j], gNi[mt]);
                    }
                }
            }
            {   // kc 8..15: gate Z only (8 frags prefetched)
                bf16x8 wz[8];
                #pragma unroll
                for (int j = 0; j < 8; ++j)
                    wz[j] = *reinterpret_cast<const bf16x8*>(WZ + (8 + j) * 512);
                #pragma unroll
                for (int j = 0; j < 8; ++j) {
                    const int kc = 8 + j;
                    bf16x8 ah[4];
                    #pragma unroll
                    for (int mt = 0; mt < 4; ++mt)
                        ah[mt] = *reinterpret_cast<const bf16x8*>(&xh[(mt * 16 + kc) * 512 + lofs]);
                    #pragma unroll
                    for (int mt = 0; mt < 4; ++mt)
                        gZ[mt] = MFMA(ah[mt], wz[j], gZ[mt]);
                }
            }
            const float bz_b = b_ih[o + 256] + b_hh[o + 256];
            const float bni  = b_ih[o + 512];
            #pragma unroll
            for (int mt = 0; mt < 4; ++mt) {
                u32 pk0 = 0, pk1 = 0;
                #pragma unroll
                for (int i = 0; i < 4; ++i) {
                    const int rl = mt * 16 + quad * 4 + i;
                    const float hv = b2f(xh[fidx(rl, 256 + o)]);
                    const float zg = sigm(gZ[mt][i] + bz_b);
                    const float n  = tanh_(gNi[mt][i] + bni + rhn[mt][i]);
                    const float hn = n + zg * (hv - n);
                    const u32 hb = f2b(hn);
                    if (i == 0) pk0 = hb;
                    else if (i == 1) pk0 |= hb << 16;
                    else if (i == 2) pk1 = hb;
                    else pk1 |= hb << 16;
                }
                pk[mt * 2]     = pk0;
                pk[mt * 2 + 1] = pk1;
            }
        }
    };

    gru_tile(0, hnp0);
    __builtin_amdgcn_sched_barrier(0);   // keep the two tiles' live ranges separate
    gru_tile(1, hnp1);

    __syncthreads();   // all reads of x and old-h complete

    // scatter h_new into the h region (overwrite old h)
    auto scat = [&](const int ot, const u32 (&pk)[8]) {
        const int o = (w * 2 + ot) * 16 + l16;
        #pragma unroll
        for (int mt = 0; mt < 4; ++mt) {
            #pragma unroll
            for (int p = 0; p < 2; ++p) {
                const u32 v = pk[mt * 2 + p];
                const int rl = mt * 16 + quad * 4 + p * 2;
                xh[fidx(rl,     256 + o)] = (u16)v;
                xh[fidx(rl + 1, 256 + o)] = (u16)(v >> 16);
            }
        }
    };
    scat(0, hnp0);
    scat(1, hnp1);
    __syncthreads();

    // coalesced h_new -> global (bf16 LDS frag layout -> fp32 stores)
    #pragma unroll
    for (int it = 0; it < 4; ++it) {
        const int idx = it * 4096 + tid * 8;
        const int r = idx >> 8, c = idx & 255;
        const bf16x8 v = *reinterpret_cast<const bf16x8*>(&xh[fidx(r, 256 + c)]);
        float4 f0, f1;
        f0.x = b2f((u16)v[0]); f0.y = b2f((u16)v[1]); f0.z = b2f((u16)v[2]); f0.w = b2f((u16)v[3]);
        f1.x = b2f((u16)v[4]); f1.y = b2f((u16)v[5]); f1.z = b2f((u16)v[6]); f1.w = b2f((u16)v[7]);
        float* dst = h_out + (size_t)(row0 + r) * 256 + c;
        *reinterpret_cast<float4*>(dst)     = f0;
        *reinterpret_cast<float4*>(dst + 4) = f1;
    }

    // ================= Stage 4: y = relu(h_new @ W_o1^T + b_o1) -> x region =================
    #pragma unroll 1
    for (int ot = 0; ot < 2; ++ot) {
        const int T = w * 2 + ot;
        const int o = T * 16 + l16;
        f32x4 aY[4];
        #pragma unroll
        for (int mt = 0; mt < 4; ++mt) aY[mt] = {0.f, 0.f, 0.f, 0.f};
        bf16x8 wo[8];
        #pragma unroll
        for (int kc = 0; kc < 8; ++kc)
            wo[kc] = *reinterpret_cast<const bf16x8*>(ws + OFF_WO1 + (T * 8 + kc) * 512 + lofs);
        #pragma unroll
        for (int kc = 0; kc < 8; ++kc) {
            bf16x8 ah2[4];
            #pragma unroll
            for (int mt = 0; mt < 4; ++mt)
                ah2[mt] = *reinterpret_cast<const bf16x8*>(&xh[(mt * 16 + 8 + kc) * 512 + lofs]);
            #pragma unroll
            for (int mt = 0; mt < 4; ++mt)
                aY[mt] = MFMA(ah2[mt], wo[kc], aY[mt]);
        }
        const float bo1 = b_o1[o];
        #pragma unroll
        for (int mt = 0; mt < 4; ++mt)
            #pragma unroll
            for (int i = 0; i < 4; ++i) {
                const int rl = mt * 16 + quad * 4 + i;
                xh[fidx(rl, o)] = f2b(fmaxf(aY[mt][i] + bo1, 0.f));
            }
    }
    __syncthreads();

    // ================= Stage 5: z_next = y @ W_o2^T + b_o2 =================
    {
        const int colt = w & 3;          // 4 col tiles of 16 -> 64 output cols
        const int rh   = w >> 2;         // row half (0: rows 0-31, 1: rows 32-63)
        const int o = colt * 16 + l16;
        f32x4 aO[2];
        aO[0] = {0.f, 0.f, 0.f, 0.f};
        aO[1] = {0.f, 0.f, 0.f, 0.f};
        bf16x8 wo2[8];
        #pragma unroll
        for (int kc = 0; kc < 8; ++kc)
            wo2[kc] = *reinterpret_cast<const bf16x8*>(ws + OFF_WO2 + (colt * 8 + kc) * 512 + lofs);
        #pragma unroll
        for (int kc = 0; kc < 8; ++kc) {
            bf16x8 ay[2];
            #pragma unroll
            for (int mt = 0; mt < 2; ++mt)
                ay[mt] = *reinterpret_cast<const bf16x8*>(&xh[((rh * 2 + mt) * 16 + kc) * 512 + lofs]);
            aO[0] = MFMA(ay[0], wo2[kc], aO[0]);
            aO[1] = MFMA(ay[1], wo2[kc], aO[1]);
        }
        const float bz2 = b_o2[o];
        #pragma unroll
        for (int mt = 0; mt < 2; ++mt)
            #pragma unroll
            for (int i = 0; i < 4; ++i) {
                const int rl = rh * 32 + mt * 16 + quad * 4 + i;
                zn_out[(size_t)(row0 + rl) * 64 + o] = aO[mt][i] + bz2;
            }
    }
}

extern "C" void kernel_launch(void* const* d_in, const int* in_sizes, int n_in,
                              void* d_out, int out_size, void* d_ws, size_t ws_size,
                              hipStream_t stream) {
    const float* z    = (const float*)d_in[0];
    const float* act  = (const float*)d_in[1];
    const float* hid  = (const float*)d_in[2];
    const float* W_in = (const float*)d_in[3];
    const float* b_in = (const float*)d_in[4];
    const float* W_ih = (const float*)d_in[5];
    const float* W_hh = (const float*)d_in[6];
    const float* b_ih = (const float*)d_in[7];
    const float* b_hh = (const float*)d_in[8];
    const float* W_o1 = (const float*)d_in[9];
    const float* b_o1 = (const float*)d_in[10];
    const float* W_o2 = (const float*)d_in[11];
    const float* b_o2 = (const float*)d_in[12];

    u16* ws = (u16*)d_ws;

    float* zn_out = (float*)d_out;                      // [B, 64]
    float* h_out  = zn_out + (size_t)B_TOT * 64;        // [1, B, 256]

    ldm_prep<<<dim3((WS_TOT + 255) / 256), dim3(256), 0, stream>>>(
        W_in, W_ih, W_hh, W_o1, W_o2, ws);

    ldm_fused<<<dim3(B_TOT / BM), dim3(512), 0, stream>>>(
        z, act, hid, W_in, b_in, b_ih, b_hh, b_o1, b_o2, ws, zn_out, h_out);
}

// Round 4
// 450.444 us; speedup vs baseline: 3.2423x; 1.0571x over previous
//
#include <hip/hip_runtime.h>

// LatentDynamicsModel fused: in-proj + GRU cell + out-proj.
// I/O fp32; internal GEMM math bf16 MFMA with fp32 accum.
// B=131072, HID=256, LATENT=64, ACTION=2.
// v5 (from v4):
//  - Stage B merged into a SINGLE K-pass per 16-col tile: all 4 gate accs live
//    (64 regs), A-frags read once and shared by 3 gates -> LDS A-traffic halved,
//    12 independent MFMA chains per kc. Peak live regs ~115 < 128 cap.
//  - float->bf16 via hardware v_cvt_pk_bf16_f32 (RNE, numerics identical) on all
//    bulk paths (z load, hidden->LDS, h_new packing).
//  - zn_next stored via LDS transpose (stride 68, reuses xh) -> one contiguous
//    256B store per row instead of strided 4B lane stores.
//  - Weights remain frag-linear in ws (v4 prep unchanged); xh frag-linear LDS.

typedef unsigned short u16;
typedef unsigned int u32;
using bf16x8 = __attribute__((ext_vector_type(8))) short;  // 8 bf16 (4 VGPRs)
using f32x4  = __attribute__((ext_vector_type(4))) float;  // 4 fp32 acc
using u16x4  = __attribute__((ext_vector_type(4))) unsigned short;

constexpr int B_TOT = 131072;
constexpr int BM    = 64;    // batch rows per block

// frag-linear ws layout (u16 units). A (tile,kc) block = 64 lanes x 8 u16 = 512.
constexpr int OFF_WIN = 0;                  // 16 tiles x 2 kc x 512 = 16384
constexpr int OFF_WG  = 16384;              // 48 gate-tiles x 16 kc x 512 ([Wih|Whh] per gate r,z,n)
constexpr int OFF_WO1 = 409600;             // 16 tiles x 8 kc x 512 = 65536
constexpr int OFF_WO2 = 475136;             // 4 tiles x 8 kc x 512 = 16384
constexpr int WS_TOT  = 491520;

__device__ __forceinline__ u16 f2b(float f) {  // RNE float->bf16 (scalar fallback)
    u32 u = __builtin_bit_cast(u32, f);
    return (u16)((u + 0x7FFFu + ((u >> 16) & 1u)) >> 16);
}
__device__ __forceinline__ u32 pkbf(float lo, float hi) {  // HW RNE pack: [bf16(lo) | bf16(hi)<<16]
    u32 r;
    asm("v_cvt_pk_bf16_f32 %0, %1, %2" : "=v"(r) : "v"(lo), "v"(hi));
    return r;
}
__device__ __forceinline__ float sigm(float x) {
    x = fminf(fmaxf(x, -30.f), 30.f);
    float e = __expf(x);
    return e * __builtin_amdgcn_rcpf(1.f + e);
}
__device__ __forceinline__ float tanh_(float x) {
    x = fminf(fmaxf(x, -15.f), 15.f);
    float e = __expf(2.f * x);
    return (e - 1.f) * __builtin_amdgcn_rcpf(e + 1.f);
}
__device__ __forceinline__ bf16x8 ld8f_bf(const float* __restrict__ p) {
    float4 a = *reinterpret_cast<const float4*>(p);
    float4 b = *reinterpret_cast<const float4*>(p + 4);
    union { u32 u[4]; bf16x8 v; } q;
    q.u[0] = pkbf(a.x, a.y); q.u[1] = pkbf(a.z, a.w);
    q.u[2] = pkbf(b.x, b.y); q.u[3] = pkbf(b.z, b.w);
    return q.v;
}
__device__ __forceinline__ float b2f(u16 u) {
    u32 x = (u32)u << 16;
    return __builtin_bit_cast(float, x);
}
// scalar element (row 0..63, virtual-k 0..511; x cols = 0..255, h cols = 256..511)
__device__ __forceinline__ int fidx(int row, int kv) {
    return ((row >> 4) * 16 + (kv >> 5)) * 512 + ((kv >> 3) & 3) * 128 + (row & 15) * 8 + (kv & 7);
}

#define MFMA(a, b, c) __builtin_amdgcn_mfma_f32_16x16x32_bf16((a), (b), (c), 0, 0, 0)

// ---------- prep: fp32 -> bf16 + swizzle into MFMA B-frag linear layout ----------
// Frag element (tile, kc, lane, e) holds W[tile*16 + (lane&15)][kc*32 + (lane>>4)*8 + e].
__global__ void ldm_prep(const float* __restrict__ W_in, const float* __restrict__ W_ih,
                         const float* __restrict__ W_hh, const float* __restrict__ W_o1,
                         const float* __restrict__ W_o2, u16* __restrict__ ws)
{
    int i = blockIdx.x * blockDim.x + threadIdx.x;
    if (i >= WS_TOT) return;
    const int lane = (i >> 3) & 63;
    const int e    = i & 7;
    const int lrow = lane & 15;
    const int kq   = (lane >> 4) * 8 + e;     // k offset within the 32-wide kc block
    float v;
    if (i < OFF_WG) {                          // W_in (K=64, 2 kc blocks per tile)
        const int blk = i >> 9;
        const int kc = blk & 1, t = blk >> 1;
        v = W_in[(t * 16 + lrow) * 66 + kc * 32 + kq];
    } else if (i < OFF_WO1) {                  // gates: [Wih | Whh], K=512 (16 kc blocks)
        const int j = i - OFF_WG;
        const int blk = j >> 9;
        const int kc16 = blk & 15, gt = blk >> 4;
        const int g = gt >> 4, t = gt & 15;
        const int grow = g * 256 + t * 16 + lrow;
        const int k = (kc16 & 7) * 32 + kq;
        v = (kc16 < 8) ? W_ih[grow * 256 + k] : W_hh[grow * 256 + k];
    } else if (i < OFF_WO2) {                  // W_o1 (K=256, 8 kc blocks)
        const int j = i - OFF_WO1;
        const int blk = j >> 9;
        const int kc = blk & 7, t = blk >> 3;
        v = W_o1[(t * 16 + lrow) * 256 + kc * 32 + kq];
    } else {                                   // W_o2 (64 rows, K=256)
        const int j = i - OFF_WO2;
        const int blk = j >> 9;
        const int kc = blk & 7, t = blk >> 3;
        v = W_o2[(t * 16 + lrow) * 256 + kc * 32 + kq];
    }
    ws[i] = f2b(v);
}

// ---------- main fused kernel ----------
__global__ __launch_bounds__(512, 4)
void ldm_fused(const float* __restrict__ z, const float* __restrict__ act,
               const float* __restrict__ hid,
               const float* __restrict__ W_in_f, const float* __restrict__ b_in,
               const float* __restrict__ b_ih, const float* __restrict__ b_hh,
               const float* __restrict__ b_o1, const float* __restrict__ b_o2,
               const u16* __restrict__ ws,
               float* __restrict__ zn_out, float* __restrict__ h_out)
{
    // merged frag-linear activation buffer: virtual-k 0..255 = x, 256..511 = h (64KB)
    __shared__ u16 xh[4 * 16 * 512];

    const int tid  = threadIdx.x;
    const int w    = tid >> 6;      // wave 0..7
    const int lane = tid & 63;
    const int l16  = lane & 15;
    const int quad = lane >> 4;
    const int row0 = blockIdx.x * BM;
    const int lofs = lane * 8;      // u16 offset of this lane's frag slot

    // ---- issue cooperative hidden load early (64 rows x 256 f32 = 64KB) ----
    const int hr  = tid >> 3;
    const int hc0 = (tid & 7) * 32;
    float4 hreg[8];
    {
        const float* hp = hid + (size_t)(row0 + hr) * 256 + hc0;
        #pragma unroll
        for (int i = 0; i < 8; ++i)
            hreg[i] = reinterpret_cast<const float4*>(hp)[i];
    }

    // ================= Stage A: x = relu([z|action] @ W_in^T + b_in) =================
    {
        bf16x8 az[4][2];  // [m-tile][k-chunk]
        #pragma unroll
        for (int mt = 0; mt < 4; ++mt) {
            const float* zp = z + (size_t)(row0 + mt * 16 + l16) * 64 + quad * 8;
            az[mt][0] = ld8f_bf(zp);
            az[mt][1] = ld8f_bf(zp + 32);
        }
        #pragma unroll
        for (int ot = 0; ot < 2; ++ot) {
            const int T = w * 2 + ot;
            const int orow = T * 16 + l16;  // output col / W_in row
            bf16x8 bw[2];
            #pragma unroll
            for (int kc = 0; kc < 2; ++kc)
                bw[kc] = *reinterpret_cast<const bf16x8*>(ws + OFF_WIN + (T * 2 + kc) * 512 + lofs);
            f32x4 acc[4];
            #pragma unroll
            for (int mt = 0; mt < 4; ++mt) acc[mt] = {0.f, 0.f, 0.f, 0.f};
            #pragma unroll
            for (int kc = 0; kc < 2; ++kc)
                #pragma unroll
                for (int mt = 0; mt < 4; ++mt)
                    acc[mt] = MFMA(az[mt][kc], bw[kc], acc[mt]);
            const float w64v = W_in_f[orow * 66 + 64];
            const float w65v = W_in_f[orow * 66 + 65];
            const float bi   = b_in[orow];
            #pragma unroll
            for (int mt = 0; mt < 4; ++mt) {
                #pragma unroll
                for (int i = 0; i < 4; ++i) {
                    const int rl = mt * 16 + quad * 4 + i;
                    const float2 av = reinterpret_cast<const float2*>(act)[row0 + rl];
                    float v = acc[mt][i] + av.x * w64v + av.y * w65v + bi;
                    xh[fidx(rl, orow)] = f2b(fmaxf(v, 0.f));
                }
            }
        }
    }

    // ---- hidden -> LDS (bf16, frag layout, virtual-k 256+c) ----
    {
        #pragma unroll
        for (int i = 0; i < 8; ++i) {
            union { u32 u[2]; u16x4 v; } q;
            q.u[0] = pkbf(hreg[i].x, hreg[i].y);
            q.u[1] = pkbf(hreg[i].z, hreg[i].w);
            *reinterpret_cast<u16x4*>(&xh[fidx(hr, 256 + hc0 + i * 4)]) = q.v;
        }
    }
    __syncthreads();

    // ================= Stage B: GRU gates, SINGLE merged K-pass per 16-col tile ====
    // Streams (frag-linear): WR/WZ full K=512 ([Wih_g | Whh_g]); WN: kc0..7 = Wih_n
    // (-> gNi), kc8..15 = Whh_n (-> gNh). A-frags read once, shared by 3 gates.
    u32 hnp0[8], hnp1[8];

    auto gru_tile = [&](const int ot, u32 (&pk)[8]) {
        const int T = w * 2 + ot;
        const int o = T * 16 + l16;                 // output col
        const u16* WR = ws + OFF_WG + (size_t)((0  + T) * 16) * 512 + lofs;
        const u16* WZ = ws + OFF_WG + (size_t)((16 + T) * 16) * 512 + lofs;
        const u16* WN = ws + OFF_WG + (size_t)((32 + T) * 16) * 512 + lofs;

        f32x4 gR[4], gZ[4], gNi[4], gNh[4];
        #pragma unroll
        for (int mt = 0; mt < 4; ++mt) {
            gR[mt]  = {0.f, 0.f, 0.f, 0.f};
            gZ[mt]  = {0.f, 0.f, 0.f, 0.f};
            gNi[mt] = {0.f, 0.f, 0.f, 0.f};
            gNh[mt] = {0.f, 0.f, 0.f, 0.f};
        }

        // one kc step: 4 A-frags (2 at a time) x 3 gates = 12 MFMAs
        auto step = [&](const int kc, const bf16x8& wr_, const bf16x8& wz_,
                        const bf16x8& wn_, f32x4 (&gNt)[4]) {
            bf16x8 a0 = *reinterpret_cast<const bf16x8*>(&xh[(0 * 16 + kc) * 512 + lofs]);
            bf16x8 a1 = *reinterpret_cast<const bf16x8*>(&xh[(1 * 16 + kc) * 512 + lofs]);
            gR[0]  = MFMA(a0, wr_, gR[0]);
            gZ[0]  = MFMA(a0, wz_, gZ[0]);
            gNt[0] = MFMA(a0, wn_, gNt[0]);
            gR[1]  = MFMA(a1, wr_, gR[1]);
            gZ[1]  = MFMA(a1, wz_, gZ[1]);
            gNt[1] = MFMA(a1, wn_, gNt[1]);
            bf16x8 a2 = *reinterpret_cast<const bf16x8*>(&xh[(2 * 16 + kc) * 512 + lofs]);
            bf16x8 a3 = *reinterpret_cast<const bf16x8*>(&xh[(3 * 16 + kc) * 512 + lofs]);
            gR[2]  = MFMA(a2, wr_, gR[2]);
            gZ[2]  = MFMA(a2, wz_, gZ[2]);
            gNt[2] = MFMA(a2, wn_, gNt[2]);
            gR[3]  = MFMA(a3, wr_, gR[3]);
            gZ[3]  = MFMA(a3, wz_, gZ[3]);
            gNt[3] = MFMA(a3, wn_, gNt[3]);
        };

        #pragma unroll
        for (int k2 = 0; k2 < 8; ++k2) {       // 2 kc per batch (6 weight frags in flight)
            const int kc0 = k2 * 2, kc1 = kc0 + 1;
            bf16x8 wr0 = *reinterpret_cast<const bf16x8*>(WR + kc0 * 512);
            bf16x8 wz0 = *reinterpret_cast<const bf16x8*>(WZ + kc0 * 512);
            bf16x8 wn0 = *reinterpret_cast<const bf16x8*>(WN + kc0 * 512);
            bf16x8 wr1 = *reinterpret_cast<const bf16x8*>(WR + kc1 * 512);
            bf16x8 wz1 = *reinterpret_cast<const bf16x8*>(WZ + kc1 * 512);
            bf16x8 wn1 = *reinterpret_cast<const bf16x8*>(WN + kc1 * 512);
            if (k2 < 4) {                       // kc 0..7: N-stream is Wih_n -> gNi
                step(kc0, wr0, wz0, wn0, gNi);
                step(kc1, wr1, wz1, wn1, gNi);
            } else {                            // kc 8..15: N-stream is Whh_n -> gNh
                step(kc0, wr0, wz0, wn0, gNh);
                step(kc1, wr1, wz1, wn1, gNh);
            }
        }

        // gate epilogue (h_new kept in registers, packed bf16 via cvt_pk)
        const float br_b = b_ih[o]       + b_hh[o];
        const float bz_b = b_ih[o + 256] + b_hh[o + 256];
        const float bni  = b_ih[o + 512];
        const float bnh  = b_hh[o + 512];
        #pragma unroll
        for (int mt = 0; mt < 4; ++mt) {
            float hn[4];
            #pragma unroll
            for (int i = 0; i < 4; ++i) {
                const int rl = mt * 16 + quad * 4 + i;
                const float hv = b2f(xh[fidx(rl, 256 + o)]);
                const float r  = sigm(gR[mt][i] + br_b);
                const float zg = sigm(gZ[mt][i] + bz_b);
                const float n  = tanh_(gNi[mt][i] + bni + r * (gNh[mt][i] + bnh));
                hn[i] = n + zg * (hv - n);
            }
            pk[mt * 2]     = pkbf(hn[0], hn[1]);
            pk[mt * 2 + 1] = pkbf(hn[2], hn[3]);
        }
    };

    gru_tile(0, hnp0);
    __builtin_amdgcn_sched_barrier(0);   // keep the two tiles' live ranges separate
    gru_tile(1, hnp1);

    __syncthreads();   // all reads of x and old-h complete

    // scatter h_new into the h region (overwrite old h)
    auto scat = [&](const int ot, const u32 (&pk)[8]) {
        const int o = (w * 2 + ot) * 16 + l16;
        #pragma unroll
        for (int mt = 0; mt < 4; ++mt) {
            #pragma unroll
            for (int p = 0; p < 2; ++p) {
                const u32 v = pk[mt * 2 + p];
                const int rl = mt * 16 + quad * 4 + p * 2;
                xh[fidx(rl,     256 + o)] = (u16)v;
                xh[fidx(rl + 1, 256 + o)] = (u16)(v >> 16);
            }
        }
    };
    scat(0, hnp0);
    scat(1, hnp1);
    __syncthreads();

    // coalesced h_new -> global (bf16 LDS frag layout -> fp32 stores)
    #pragma unroll
    for (int it = 0; it < 4; ++it) {
        const int idx = it * 4096 + tid * 8;
        const int r = idx >> 8, c = idx & 255;
        const bf16x8 v = *reinterpret_cast<const bf16x8*>(&xh[fidx(r, 256 + c)]);
        float4 f0, f1;
        f0.x = b2f((u16)v[0]); f0.y = b2f((u16)v[1]); f0.z = b2f((u16)v[2]); f0.w = b2f((u16)v[3]);
        f1.x = b2f((u16)v[4]); f1.y = b2f((u16)v[5]); f1.z = b2f((u16)v[6]); f1.w = b2f((u16)v[7]);
        float* dst = h_out + (size_t)(row0 + r) * 256 + c;
        *reinterpret_cast<float4*>(dst)     = f0;
        *reinterpret_cast<float4*>(dst + 4) = f1;
    }

    // ================= Stage 4: y = relu(h_new @ W_o1^T + b_o1) -> x region =================
    #pragma unroll 1
    for (int ot = 0; ot < 2; ++ot) {
        const int T = w * 2 + ot;
        const int o = T * 16 + l16;
        f32x4 aY[4];
        #pragma unroll
        for (int mt = 0; mt < 4; ++mt) aY[mt] = {0.f, 0.f, 0.f, 0.f};
        bf16x8 wo[8];
        #pragma unroll
        for (int kc = 0; kc < 8; ++kc)
            wo[kc] = *reinterpret_cast<const bf16x8*>(ws + OFF_WO1 + (T * 8 + kc) * 512 + lofs);
        #pragma unroll
        for (int kc = 0; kc < 8; ++kc) {
            bf16x8 ah2[4];
            #pragma unroll
            for (int mt = 0; mt < 4; ++mt)
                ah2[mt] = *reinterpret_cast<const bf16x8*>(&xh[(mt * 16 + 8 + kc) * 512 + lofs]);
            #pragma unroll
            for (int mt = 0; mt < 4; ++mt)
                aY[mt] = MFMA(ah2[mt], wo[kc], aY[mt]);
        }
        const float bo1 = b_o1[o];
        #pragma unroll
        for (int mt = 0; mt < 4; ++mt)
            #pragma unroll
            for (int i = 0; i < 4; ++i) {
                const int rl = mt * 16 + quad * 4 + i;
                xh[fidx(rl, o)] = f2b(fmaxf(aY[mt][i] + bo1, 0.f));
            }
    }
    __syncthreads();

    // ================= Stage 5: z_next = y @ W_o2^T + b_o2 (LDS-transposed store) ==
    {
        const int colt = w & 3;          // 4 col tiles of 16 -> 64 output cols
        const int rh   = w >> 2;         // row half (0: rows 0-31, 1: rows 32-63)
        const int o = colt * 16 + l16;
        f32x4 aO[2];
        aO[0] = {0.f, 0.f, 0.f, 0.f};
        aO[1] = {0.f, 0.f, 0.f, 0.f};
        bf16x8 wo2[8];
        #pragma unroll
        for (int kc = 0; kc < 8; ++kc)
            wo2[kc] = *reinterpret_cast<const bf16x8*>(ws + OFF_WO2 + (colt * 8 + kc) * 512 + lofs);
        #pragma unroll
        for (int kc = 0; kc < 8; ++kc) {
            bf16x8 ay[2];
            #pragma unroll
            for (int mt = 0; mt < 2; ++mt)
                ay[mt] = *reinterpret_cast<const bf16x8*>(&xh[((rh * 2 + mt) * 16 + kc) * 512 + lofs]);
            aO[0] = MFMA(ay[0], wo2[kc], aO[0]);
            aO[1] = MFMA(ay[1], wo2[kc], aO[1]);
        }
        const float bz2 = b_o2[o];

        __syncthreads();                 // all y reads done; xh reusable as f32 scratch
        float* zsc = reinterpret_cast<float*>(xh);   // 64 rows x stride 68 f32 (17.4KB)
        #pragma unroll
        for (int mt = 0; mt < 2; ++mt)
            #pragma unroll
            for (int i = 0; i < 4; ++i) {
                const int rl = rh * 32 + mt * 16 + quad * 4 + i;
                zsc[rl * 68 + o] = aO[mt][i] + bz2;
            }
        __syncthreads();
        const int zr = tid >> 3, zc = (tid & 7) * 8;
        float4 z0 = *reinterpret_cast<const float4*>(&zsc[zr * 68 + zc]);
        float4 z1 = *reinterpret_cast<const float4*>(&zsc[zr * 68 + zc + 4]);
        float* dst = zn_out + (size_t)(row0 + zr) * 64 + zc;
        *reinterpret_cast<float4*>(dst)     = z0;
        *reinterpret_cast<float4*>(dst + 4) = z1;
    }
}

extern "C" void kernel_launch(void* const* d_in, const int* in_sizes, int n_in,
                              void* d_out, int out_size, void* d_ws, size_t ws_size,
                              hipStream_t stream) {
    const float* z    = (const float*)d_in[0];
    const float* act  = (const float*)d_in[1];
    const float* hid  = (const float*)d_in[2];
    const float* W_in = (const float*)d_in[3];
    const float* b_in = (const float*)d_in[4];
    const float* W_ih = (const float*)d_in[5];
    const float* W_hh = (const float*)d_in[6];
    const float* b_ih = (const float*)d_in[7];
    const float* b_hh = (const float*)d_in[8];
    const float* W_o1 = (const float*)d_in[9];
    const float* b_o1 = (const float*)d_in[10];
    const float* W_o2 = (const float*)d_in[11];
    const float* b_o2 = (const float*)d_in[12];

    u16* ws = (u16*)d_ws;

    float* zn_out = (float*)d_out;                      // [B, 64]
    float* h_out  = zn_out + (size_t)B_TOT * 64;        // [1, B, 256]

    ldm_prep<<<dim3((WS_TOT + 255) / 256), dim3(256), 0, stream>>>(
        W_in, W_ih, W_hh, W_o1, W_o2, ws);

    ldm_fused<<<dim3(B_TOT / BM), dim3(512), 0, stream>>>(
        z, act, hid, W_in, b_in, b_ih, b_hh, b_o1, b_o2, ws, zn_out, h_out);
}